// Round 4
// baseline (851.892 us; speedup 1.0000x reference)
//
#include <hip/hip_runtime.h>

// Problem constants (fixed by reference setup_inputs)
constexpr int B = 16;
constexpr int C = 256;
constexpr int T = 16000;
constexpr int Q = T / 4;            // float4 columns per (b,c) row = 4000
constexpr int WSEG = 16;            // t4 columns per window (64 t scalars)
constexpr int NSEG = Q / WSEG;      // 250 windows per b (exact)
constexpr float EPS = 1e-8f;
constexpr int NFLAG = B * NSEG;     // 4000

typedef float f4 __attribute__((ext_vector_type(4)));

#define SCOPE_AGENT __HIP_MEMORY_SCOPE_AGENT

__device__ inline f4 shfl_xor_f4(f4 v, int m) {
  f4 r;
  r[0] = __shfl_xor(v[0], m); r[1] = __shfl_xor(v[1], m);
  r[2] = __shfl_xor(v[2], m); r[3] = __shfl_xor(v[3], m);
  return r;
}

// Zero lookback flags + the block-order ticket (ws is poisoned every iter).
__global__ __launch_bounds__(256) void init_flags(int* __restrict__ flags,
                                                  int* __restrict__ ticket) {
  const int i = blockIdx.x * 256 + threadIdx.x;
  if (i < NFLAG) flags[i] = 0;
  if (i == 0) *ticket = 0;
}

// ---------------------------------------------------------------------------
// Single-pass fused cumulative-LN, decoupled lookback with ORDERED BLOCK IDs.
// HW dispatch order is undefined on 8-XCD gfx950 (round-3 livelock), so each
// block draws vid = atomicAdd(ticket): resident blocks always hold the lowest
// outstanding vids -> every spin's predecessors are resident-or-done ->
// guaranteed forward progress regardless of dispatch order.
//
// Block vid -> (b = vid/NSEG, seg = vid%NSEG): 256 threads = 4 waves.
// Thread (w, l): col = l&15 (t4 within window), r = l>>4. Thread holds 16
// f4s: channels c = r + 4w + 16k at fixed t4 -> 16-lane 256B contiguous
// segments (coalesced), whole 64KB window in registers (x read ONCE).
// Channel reduce: shfl_xor(16,32) + LDS across waves. Window scan fp32
// (64-t spans); cross-window prefix in double via lookback (agent-scope
// acquire/release for cross-XCD visibility).
// ---------------------------------------------------------------------------
__global__ __launch_bounds__(256) void fused_kernel(
    const float* __restrict__ x,
    const float* __restrict__ gain,
    const float* __restrict__ bias,
    float* __restrict__ out,
    int* __restrict__ flags,
    int* __restrict__ ticket,
    double* __restrict__ agg_s, double* __restrict__ agg_p,
    double* __restrict__ inc_s, double* __restrict__ inc_p) {
  __shared__ int vid_sh;
  if (threadIdx.x == 0) vid_sh = atomicAdd(ticket, 1);
  __syncthreads();
  const int vid = vid_sh;
  const int b   = vid / NSEG;
  const int seg = vid - b * NSEG;

  const int w   = threadIdx.x >> 6;
  const int l   = threadIdx.x & 63;
  const int col = l & 15;
  const int r   = l >> 4;
  const int t4  = seg * WSEG + col;
  const int fb  = b * NSEG;

  // ---- load window into registers + per-thread channel partial sums ----
  const f4* xb = reinterpret_cast<const f4*>(x + (size_t)b * C * T);
  f4 v[16];
  f4 s = {0.f, 0.f, 0.f, 0.f}, p = {0.f, 0.f, 0.f, 0.f};
#pragma unroll
  for (int k = 0; k < 16; ++k) {
    const int c = r + 4 * w + 16 * k;
    v[k] = __builtin_nontemporal_load(&xb[(size_t)c * Q + t4]);
    s += v[k];
    p += v[k] * v[k];
  }
  // reduce across r-groups (lanes differing in bits 4,5 share a t4 column)
  s += shfl_xor_f4(s, 16); p += shfl_xor_f4(p, 16);
  s += shfl_xor_f4(s, 32); p += shfl_xor_f4(p, 32);

  __shared__ f4 lss[4][16], lsp[4][16];
  __shared__ f4 incl_s_l[16], incl_p_l[16];
  __shared__ double excl_sh[2];
  if (l < 16) { lss[w][col] = s; lsp[w][col] = p; }
  __syncthreads();

  if (w == 0) {
    // ---- window-local inclusive scan ----
    f4 cs = lss[0][col] + lss[1][col] + lss[2][col] + lss[3][col];
    f4 cp = lsp[0][col] + lsp[1][col] + lsp[2][col] + lsp[3][col];
    cs[1] += cs[0]; cs[2] += cs[1]; cs[3] += cs[2];
    cp[1] += cp[0]; cp[2] += cp[1]; cp[3] += cp[2];
    const float ts = cs[3], tp = cp[3];
    float ps = ts, pp = tp;
#pragma unroll
    for (int off = 1; off < 16; off <<= 1) {
      const float ns = __shfl_up(ps, off, 16);
      const float np = __shfl_up(pp, off, 16);
      if (col >= off) { ps += ns; pp += np; }
    }
    const float es = ps - ts, ep = pp - tp;   // exclusive prefix within window
    cs += es; cp += ep;                       // window-inclusive per t
    if (l < 16) { incl_s_l[col] = cs; incl_p_l[col] = cp; }
    const double wtot_s = (double)__shfl(ps, 15, 16);  // window total
    const double wtot_p = (double)__shfl(pp, 15, 16);

    // ---- decoupled lookback (wave 0, 64-wide, doubles) ----
    double ex_s = 0.0, ex_p = 0.0;
    if (seg > 0) {
      if (l == 0) {
        __hip_atomic_store(&agg_s[fb + seg], wtot_s, __ATOMIC_RELAXED, SCOPE_AGENT);
        __hip_atomic_store(&agg_p[fb + seg], wtot_p, __ATOMIC_RELAXED, SCOPE_AGENT);
        __hip_atomic_store(&flags[fb + seg], 1, __ATOMIC_RELEASE, SCOPE_AGENT);
      }
      int base = seg - 1;
      for (;;) {
        const int idx = base - l;   // lane l inspects predecessor idx
        int f;
        for (;;) {
          f = (idx >= 0) ? __hip_atomic_load(&flags[fb + idx], __ATOMIC_ACQUIRE,
                                             SCOPE_AGENT)
                         : 2;
          if (__all(f != 0)) break;
          __builtin_amdgcn_s_sleep(1);
        }
        const unsigned long long m2 = __ballot(f == 2);
        const int j0 = m2 ? (__ffsll((long long)m2) - 1) : 64;
        double c_s = 0.0, c_p = 0.0;
        if (idx >= 0) {
          if (l < j0) {          // aggregates strictly after nearest inclusive
            c_s = __hip_atomic_load(&agg_s[fb + idx], __ATOMIC_RELAXED, SCOPE_AGENT);
            c_p = __hip_atomic_load(&agg_p[fb + idx], __ATOMIC_RELAXED, SCOPE_AGENT);
          } else if (l == j0) {  // nearest published inclusive prefix
            c_s = __hip_atomic_load(&inc_s[fb + idx], __ATOMIC_RELAXED, SCOPE_AGENT);
            c_p = __hip_atomic_load(&inc_p[fb + idx], __ATOMIC_RELAXED, SCOPE_AGENT);
          }
        }
#pragma unroll
        for (int off = 32; off > 0; off >>= 1) {
          c_s += __shfl_xor(c_s, off);
          c_p += __shfl_xor(c_p, off);
        }
        ex_s += c_s; ex_p += c_p;
        if (m2) break;           // consumed an inclusive -> prefix complete
        base -= 64;
        if (base < 0) break;     // unreachable (seg 0 publishes inclusive only)
      }
    }
    if (l == 0) {
      __hip_atomic_store(&inc_s[fb + seg], ex_s + wtot_s, __ATOMIC_RELAXED, SCOPE_AGENT);
      __hip_atomic_store(&inc_p[fb + seg], ex_p + wtot_p, __ATOMIC_RELAXED, SCOPE_AGENT);
      __hip_atomic_store(&flags[fb + seg], 2, __ATOMIC_RELEASE, SCOPE_AGENT);
      excl_sh[0] = ex_s; excl_sh[1] = ex_p;
    }
  }
  __syncthreads();

  // ---- normalize from registers and store ----
  const double exs = excl_sh[0];
  const double exq = excl_sh[1];
  const f4 ws = incl_s_l[col];
  const f4 wp = incl_p_l[col];
  f4 mm, ii;
#pragma unroll
  for (int i = 0; i < 4; ++i) {
    const int t = t4 * 4 + i;
    const float cnt  = (float)(t + 1) * (float)C;   // exact in fp32 (< 2^24)
    const float cums = (float)(exs + (double)ws[i]);
    const float cump = (float)(exq + (double)wp[i]);
    const float mean = cums / cnt;
    const float var  = cump / cnt - mean * mean;
    mm[i] = mean;
    ii[i] = rsqrtf(var + EPS);
  }
  f4* ob = reinterpret_cast<f4*>(out + (size_t)b * C * T);
#pragma unroll
  for (int k = 0; k < 16; ++k) {
    const int c = r + 4 * w + 16 * k;
    const f4 o = (v[k] - mm) * ii * gain[c] + bias[c];
    __builtin_nontemporal_store(o, &ob[(size_t)c * Q + t4]);
  }
}

extern "C" void kernel_launch(void* const* d_in, const int* in_sizes, int n_in,
                              void* d_out, int out_size, void* d_ws, size_t ws_size,
                              hipStream_t stream) {
  const float* x    = (const float*)d_in[0];
  const float* gain = (const float*)d_in[1];
  const float* bias = (const float*)d_in[2];
  float* out = (float*)d_out;

  // ws: agg_s | agg_p | inc_s | inc_p (doubles, NFLAG each) | flags | ticket
  double* agg_s = (double*)d_ws;
  double* agg_p = agg_s + NFLAG;
  double* inc_s = agg_p + NFLAG;
  double* inc_p = inc_s + NFLAG;
  int*    flags = (int*)(inc_p + NFLAG);
  int*    ticket = flags + NFLAG;

  init_flags<<<(NFLAG + 255) / 256, 256, 0, stream>>>(flags, ticket);

  fused_kernel<<<NFLAG, 256, 0, stream>>>(x, gain, bias, out, flags, ticket,
                                          agg_s, agg_p, inc_s, inc_p);
}

// Round 5
// 471.079 us; speedup vs baseline: 1.8084x; 1.8084x over previous
//
#include <hip/hip_runtime.h>

// Problem constants (fixed by reference setup_inputs)
constexpr int B = 16;
constexpr int C = 256;
constexpr int T = 16000;
constexpr int Q = T / 4;            // float4 columns per (b,c) row = 4000
constexpr int WSEG = 16;            // t4 columns per window (64 t scalars)
constexpr int NSEG = Q / WSEG;      // 250 windows per b (exact)
constexpr float EPS = 1e-8f;
constexpr int NFLAG = B * NSEG;     // 4000

typedef float f4 __attribute__((ext_vector_type(4)));

#define SCOPE_AGENT __HIP_MEMORY_SCOPE_AGENT
#define RLX __ATOMIC_RELAXED

__device__ inline f4 shfl_xor_f4(f4 v, int m) {
  f4 r;
  r[0] = __shfl_xor(v[0], m); r[1] = __shfl_xor(v[1], m);
  r[2] = __shfl_xor(v[2], m); r[3] = __shfl_xor(v[3], m);
  return r;
}

// Zero lookback flags + ticket (ws is poisoned before every timed iteration).
__global__ __launch_bounds__(256) void init_flags(int* __restrict__ flags,
                                                  int* __restrict__ ticket) {
  const int i = blockIdx.x * 256 + threadIdx.x;
  if (i < NFLAG) flags[i] = 0;
  if (i == 0) *ticket = 0;
}

// ---------------------------------------------------------------------------
// Single-pass fused cumulative-LN, decoupled lookback, ordered block IDs.
//
// Round-4 lesson (733 GB/s, VALUBusy 2.4%, 154 us/block latency): agent-scope
// ACQUIRE loads / RELEASE stores lower to buffer_inv / buffer_wbl2 on gfx94x.
// Polling with acquire = millions of cache-invalidate ops: serializes the CU
// memory pipe AND blows away the L1/L2 that the x stream needs. This version
// uses ONLY RELAXED agent-scope atomics (sc-bypass to the coherence point; no
// cache maintenance). Ordering:
//   publisher: value exchanges -> s_waitcnt vmcnt(0) -> flag store
//              (hand-rolled release without the L2 writeback)
//   consumer:  in-order issue: aggregate loads issue only after the flag
//              ballot consumed the flag values; relaxed agent loads read the
//              coherence point directly, so no staleness.
// Ticket-ordered vids (round-3 lesson): resident blocks always hold the
// lowest outstanding vids -> lookback predecessors are resident-or-done ->
// forward progress regardless of HW dispatch order.
//
// Block vid -> (b, seg). Thread (w, l): col=l&15 (t4 in window), r=l>>4.
// Thread holds 16 f4s: channels c = r+4w+16k at fixed t4 (16-lane 256B
// contiguous segments). Whole 64KB window in registers: x read ONCE.
// x loads CACHED (L2/L3 retention works now that nothing invalidates them);
// out stores NT.
// ---------------------------------------------------------------------------
__global__ __launch_bounds__(256) void fused_kernel(
    const float* __restrict__ x,
    const float* __restrict__ gain,
    const float* __restrict__ bias,
    float* __restrict__ out,
    int* __restrict__ flags,
    int* __restrict__ ticket,
    double* __restrict__ agg_s, double* __restrict__ agg_p,
    double* __restrict__ inc_s, double* __restrict__ inc_p) {
  __shared__ int vid_sh;
  if (threadIdx.x == 0) vid_sh = __hip_atomic_fetch_add(ticket, 1, RLX, SCOPE_AGENT);
  __syncthreads();
  const int vid = vid_sh;
  const int b   = vid / NSEG;
  const int seg = vid - b * NSEG;

  const int w   = threadIdx.x >> 6;
  const int l   = threadIdx.x & 63;
  const int col = l & 15;
  const int r   = l >> 4;
  const int t4  = seg * WSEG + col;
  const int fb  = b * NSEG;

  // ---- load window into registers + per-thread channel partial sums ----
  const f4* xb = reinterpret_cast<const f4*>(x + (size_t)b * C * T);
  f4 v[16];
  f4 s = {0.f, 0.f, 0.f, 0.f}, p = {0.f, 0.f, 0.f, 0.f};
#pragma unroll
  for (int k = 0; k < 16; ++k) {
    const int c = r + 4 * w + 16 * k;
    v[k] = xb[(size_t)c * Q + t4];
    s += v[k];
    p += v[k] * v[k];
  }
  // reduce across r-groups (lanes differing in bits 4,5 share a t4 column)
  s += shfl_xor_f4(s, 16); p += shfl_xor_f4(p, 16);
  s += shfl_xor_f4(s, 32); p += shfl_xor_f4(p, 32);

  __shared__ f4 lss[4][16], lsp[4][16];
  __shared__ f4 incl_s_l[16], incl_p_l[16];
  __shared__ double excl_sh[2];
  if (l < 16) { lss[w][col] = s; lsp[w][col] = p; }
  __syncthreads();

  if (w == 0) {
    // ---- window-local inclusive scan ----
    f4 cs = lss[0][col] + lss[1][col] + lss[2][col] + lss[3][col];
    f4 cp = lsp[0][col] + lsp[1][col] + lsp[2][col] + lsp[3][col];
    cs[1] += cs[0]; cs[2] += cs[1]; cs[3] += cs[2];
    cp[1] += cp[0]; cp[2] += cp[1]; cp[3] += cp[2];
    const float ts = cs[3], tp = cp[3];
    float ps = ts, pp = tp;
#pragma unroll
    for (int off = 1; off < 16; off <<= 1) {
      const float ns = __shfl_up(ps, off, 16);
      const float np = __shfl_up(pp, off, 16);
      if (col >= off) { ps += ns; pp += np; }
    }
    const float es = ps - ts, ep = pp - tp;   // exclusive prefix within window
    cs += es; cp += ep;                       // window-inclusive per t
    if (l < 16) { incl_s_l[col] = cs; incl_p_l[col] = cp; }
    const double wtot_s = (double)__shfl(ps, 15, 16);  // window total
    const double wtot_p = (double)__shfl(pp, 15, 16);

    // ---- publish aggregate: relaxed exchanges + vmcnt drain + flag ----
    double ex_s = 0.0, ex_p = 0.0;
    if (seg > 0) {
      if (l == 0) {
        (void)__hip_atomic_exchange(&agg_s[fb + seg], wtot_s, RLX, SCOPE_AGENT);
        (void)__hip_atomic_exchange(&agg_p[fb + seg], wtot_p, RLX, SCOPE_AGENT);
        asm volatile("s_waitcnt vmcnt(0)" ::: "memory");  // values performed
        __hip_atomic_store(&flags[fb + seg], 1, RLX, SCOPE_AGENT);
      }
      // ---- decoupled lookback (wave 0, 64-wide, doubles, all relaxed) ----
      int base = seg - 1;
      for (;;) {
        const int idx = base - l;   // lane l inspects predecessor idx
        int f;
        for (;;) {
          f = (idx >= 0) ? __hip_atomic_load(&flags[fb + idx], RLX, SCOPE_AGENT)
                         : 2;
          if (__all(f != 0)) break;
          __builtin_amdgcn_s_sleep(2);
        }
        const unsigned long long m2 = __ballot(f == 2);
        const int j0 = m2 ? (__ffsll((long long)m2) - 1) : 64;
        double c_s = 0.0, c_p = 0.0;
        if (idx >= 0) {
          if (l < j0) {          // aggregates strictly after nearest inclusive
            c_s = __hip_atomic_load(&agg_s[fb + idx], RLX, SCOPE_AGENT);
            c_p = __hip_atomic_load(&agg_p[fb + idx], RLX, SCOPE_AGENT);
          } else if (l == j0) {  // nearest published inclusive prefix
            c_s = __hip_atomic_load(&inc_s[fb + idx], RLX, SCOPE_AGENT);
            c_p = __hip_atomic_load(&inc_p[fb + idx], RLX, SCOPE_AGENT);
          }
        }
#pragma unroll
        for (int off = 32; off > 0; off >>= 1) {
          c_s += __shfl_xor(c_s, off);
          c_p += __shfl_xor(c_p, off);
        }
        ex_s += c_s; ex_p += c_p;
        if (m2) break;           // consumed an inclusive -> prefix complete
        base -= 64;
        if (base < 0) break;     // unreachable (seg 0 publishes inclusive only)
      }
    }
    if (l == 0) {
      (void)__hip_atomic_exchange(&inc_s[fb + seg], ex_s + wtot_s, RLX, SCOPE_AGENT);
      (void)__hip_atomic_exchange(&inc_p[fb + seg], ex_p + wtot_p, RLX, SCOPE_AGENT);
      asm volatile("s_waitcnt vmcnt(0)" ::: "memory");  // values performed
      __hip_atomic_store(&flags[fb + seg], 2, RLX, SCOPE_AGENT);
      excl_sh[0] = ex_s; excl_sh[1] = ex_p;
    }
  }
  __syncthreads();

  // ---- normalize from registers and store ----
  const double exs = excl_sh[0];
  const double exq = excl_sh[1];
  const f4 ws = incl_s_l[col];
  const f4 wp = incl_p_l[col];
  f4 mm, ii;
#pragma unroll
  for (int i = 0; i < 4; ++i) {
    const int t = t4 * 4 + i;
    const float cnt  = (float)(t + 1) * (float)C;   // exact in fp32 (< 2^24)
    const float cums = (float)(exs + (double)ws[i]);
    const float cump = (float)(exq + (double)wp[i]);
    const float mean = cums / cnt;
    const float var  = cump / cnt - mean * mean;
    mm[i] = mean;
    ii[i] = rsqrtf(var + EPS);
  }
  f4* ob = reinterpret_cast<f4*>(out + (size_t)b * C * T);
#pragma unroll
  for (int k = 0; k < 16; ++k) {
    const int c = r + 4 * w + 16 * k;
    const f4 o = (v[k] - mm) * ii * gain[c] + bias[c];
    __builtin_nontemporal_store(o, &ob[(size_t)c * Q + t4]);
  }
}

extern "C" void kernel_launch(void* const* d_in, const int* in_sizes, int n_in,
                              void* d_out, int out_size, void* d_ws, size_t ws_size,
                              hipStream_t stream) {
  const float* x    = (const float*)d_in[0];
  const float* gain = (const float*)d_in[1];
  const float* bias = (const float*)d_in[2];
  float* out = (float*)d_out;

  // ws: agg_s | agg_p | inc_s | inc_p (doubles, NFLAG each) | flags | ticket
  double* agg_s = (double*)d_ws;
  double* agg_p = agg_s + NFLAG;
  double* inc_s = agg_p + NFLAG;
  double* inc_p = inc_s + NFLAG;
  int*    flags = (int*)(inc_p + NFLAG);
  int*    ticket = flags + NFLAG;

  init_flags<<<(NFLAG + 255) / 256, 256, 0, stream>>>(flags, ticket);

  fused_kernel<<<NFLAG, 256, 0, stream>>>(x, gain, bias, out, flags, ticket,
                                          agg_s, agg_p, inc_s, inc_p);
}